// Round 1
// baseline (1717.704 us; speedup 1.0000x reference)
//
#include <hip/hip_runtime.h>
#include <math.h>

// Problem: B=8, W=H=128, D=64, bs=4 -> rows M=8*32*32=8192, features F=1024.
// ws layout (bytes):
//   XC      @ 0         : 8192*1024 f32 = 33554432
//   YC      @ 33554432  : 8192*1024 f32 = 33554432
//   partVal @ 67108864  : 8192*8 f32    = 262144
//   partIdx @ 67371008  : 8192*8 i32    = 262144
//   bestIdx @ 67633152  : 8192 i32      = 32768
//   blkSum  @ 67665920  : 32 f32        = 128

#define NROWS 8192
#define F 1024
#define NCHUNK 8   // col chunks in sim kernel

__device__ __forceinline__ double blockReduceAdd(double v) {
    __shared__ double sh[4];
    #pragma unroll
    for (int off = 32; off; off >>= 1) v += __shfl_down(v, off, 64);
    __syncthreads();
    if ((threadIdx.x & 63) == 0) sh[threadIdx.x >> 6] = v;
    __syncthreads();
    return sh[0] + sh[1] + sh[2] + sh[3];
}

// One block per feature-row (16384 blocks: first 8192 = x, rest = y).
__global__ __launch_bounds__(256) void normKernel(
    const float* __restrict__ x, const float* __restrict__ y,
    float* __restrict__ XC, float* __restrict__ YC) {
    int bi = blockIdx.x;
    const float* src;
    float* dst;
    int row;
    if (bi < NROWS) { src = x; dst = XC; row = bi; }
    else            { src = y; dst = YC; row = bi - NROWS; }
    int t = threadIdx.x;
    int b = row >> 10, wi = (row >> 5) & 31, hi = row & 31;
    int a = t >> 6, c = (t >> 4) & 3, d = (t & 15) << 2;
    const float4 v = *(const float4*)&src[(((b * 128) + wi * 4 + a) * 128 + hi * 4 + c) * 64 + d];
    double s = (double)v.x + (double)v.y + (double)v.z + (double)v.w;
    double mean = blockReduceAdd(s) * (1.0 / 1024.0);
    double dx = (double)v.x - mean, dy = (double)v.y - mean;
    double dz = (double)v.z - mean, dw = (double)v.w - mean;
    double ss = blockReduceAdd(dx * dx + dy * dy + dz * dz + dw * dw);
    double scale = 1.0 / (sqrt(ss) + 1e-5);
    float4 o;
    o.x = (float)(dx * scale); o.y = (float)(dy * scale);
    o.z = (float)(dz * scale); o.w = (float)(dw * scale);
    *(float4*)&dst[row * F + (t << 2)] = o;
}

// Fused SGEMM (XC * YC^T) + per-row running max/argmax over a 1024-col chunk.
// BM=BN=128, BK=16, 256 threads, 8x8 per-thread register tile.
#define BM 128
#define BN 128
#define BK 16
#define LDP 132  // padded LDS row stride (BM+4), float4-aligned

__global__ __launch_bounds__(256) void simKernel(
    const float* __restrict__ XC, const float* __restrict__ YC,
    float* __restrict__ partVal, int* __restrict__ partIdx) {
    __shared__ float As[BK][LDP];
    __shared__ float Bs[BK][LDP];
    const int t = threadIdx.x;
    const int r0 = blockIdx.x * BM;      // 64 row tiles
    const int chunk = blockIdx.y;        // 8 col chunks of 1024
    const int tr = t >> 4, tc = t & 15;
    const int lr = t >> 2;               // load row 0..63
    const int lk = (t & 3) << 2;         // load k 0,4,8,12

    float bestV[8];
    int bestI[8];
    #pragma unroll
    for (int i = 0; i < 8; i++) { bestV[i] = -1e30f; bestI[i] = 0x7fffffff; }

    for (int ct = 0; ct < 8; ct++) {
        const int c0 = chunk * 1024 + ct * BN;
        float acc[8][8];
        #pragma unroll
        for (int i = 0; i < 8; i++)
            #pragma unroll
            for (int j = 0; j < 8; j++) acc[i][j] = 0.0f;

        for (int kk = 0; kk < F; kk += BK) {
            float4 a0 = *(const float4*)&XC[(r0 + lr) * F + kk + lk];
            float4 a1 = *(const float4*)&XC[(r0 + lr + 64) * F + kk + lk];
            float4 b0 = *(const float4*)&YC[(c0 + lr) * F + kk + lk];
            float4 b1 = *(const float4*)&YC[(c0 + lr + 64) * F + kk + lk];
            __syncthreads();  // previous compute done before overwrite
            As[lk + 0][lr] = a0.x; As[lk + 1][lr] = a0.y;
            As[lk + 2][lr] = a0.z; As[lk + 3][lr] = a0.w;
            As[lk + 0][lr + 64] = a1.x; As[lk + 1][lr + 64] = a1.y;
            As[lk + 2][lr + 64] = a1.z; As[lk + 3][lr + 64] = a1.w;
            Bs[lk + 0][lr] = b0.x; Bs[lk + 1][lr] = b0.y;
            Bs[lk + 2][lr] = b0.z; Bs[lk + 3][lr] = b0.w;
            Bs[lk + 0][lr + 64] = b1.x; Bs[lk + 1][lr + 64] = b1.y;
            Bs[lk + 2][lr + 64] = b1.z; Bs[lk + 3][lr + 64] = b1.w;
            __syncthreads();
            #pragma unroll
            for (int k = 0; k < BK; k++) {
                float av[8], bv[8];
                *(float4*)(av)     = *(const float4*)&As[k][tr << 2];
                *(float4*)(av + 4) = *(const float4*)&As[k][64 + (tr << 2)];
                *(float4*)(bv)     = *(const float4*)&Bs[k][tc << 2];
                *(float4*)(bv + 4) = *(const float4*)&Bs[k][64 + (tc << 2)];
                #pragma unroll
                for (int i = 0; i < 8; i++)
                    #pragma unroll
                    for (int j = 0; j < 8; j++)
                        acc[i][j] += av[i] * bv[j];
            }
        }
        // fold this col tile into running best (cols visited in ascending
        // index order; strict > keeps first-max semantics)
        #pragma unroll
        for (int i = 0; i < 8; i++) {
            #pragma unroll
            for (int j = 0; j < 8; j++) {
                int col = c0 + ((j < 4) ? ((tc << 2) + j) : (64 + (tc << 2) + j - 4));
                float v = acc[i][j];
                if (v > bestV[i]) { bestV[i] = v; bestI[i] = col; }
            }
        }
    }
    // reduce across the 16 lanes (tc) sharing the same rows
    #pragma unroll
    for (int i = 0; i < 8; i++) {
        float v = bestV[i];
        int idx = bestI[i];
        #pragma unroll
        for (int m = 1; m < 16; m <<= 1) {
            float v2 = __shfl_xor(v, m, 64);
            int i2 = __shfl_xor(idx, m, 64);
            if (v2 > v || (v2 == v && i2 < idx)) { v = v2; idx = i2; }
        }
        if (tc == 0) {
            int row = r0 + ((i < 4) ? ((tr << 2) + i) : (64 + (tr << 2) + i - 4));
            partVal[row * NCHUNK + chunk] = v;
            partIdx[row * NCHUNK + chunk] = idx;
        }
    }
}

__global__ __launch_bounds__(256) void reduceKernel(
    const float* __restrict__ partVal, const int* __restrict__ partIdx,
    int* __restrict__ bestIdx, float* __restrict__ blkSum) {
    int t = threadIdx.x;
    int row = blockIdx.x * 256 + t;
    float bv = -1e30f;
    int bi = 0x7fffffff;
    #pragma unroll
    for (int c = 0; c < NCHUNK; c++) {
        float v = partVal[row * NCHUNK + c];
        int idx = partIdx[row * NCHUNK + c];
        if (v > bv || (v == bv && idx < bi)) { bv = v; bi = idx; }
    }
    bestIdx[row] = bi;
    double s = 1.0 - (double)bv;
    __shared__ double sh[4];
    #pragma unroll
    for (int off = 32; off; off >>= 1) s += __shfl_down(s, off, 64);
    if ((t & 63) == 0) sh[t >> 6] = s;
    __syncthreads();
    if (t == 0) blkSum[blockIdx.x] = (float)(sh[0] + sh[1] + sh[2] + sh[3]);
}

// new_x[b,w,h,d] = YC[bestIdx[block(b,w,h)]][f(w%4,h%4,d)]; also finalize loss.
__global__ __launch_bounds__(256) void gatherKernel(
    const float* __restrict__ YC, const int* __restrict__ bestIdx,
    const float* __restrict__ blkSum, float* __restrict__ out) {
    int t = threadIdx.x;
    if (blockIdx.x == 0 && t == 0) {
        double s = 0.0;
        for (int i = 0; i < 32; i++) s += (double)blkSum[i];
        out[0] = (float)(s / 8192.0);
    }
    int g = (blockIdx.x * 256 + t) << 2;       // 4 elements per thread
    int b = g >> 20;
    int w = (g >> 13) & 127;
    int h = (g >> 6) & 127;
    int d = g & 63;
    int row = (b << 10) + ((w >> 2) << 5) + (h >> 2);
    int f = ((w & 3) << 8) + ((h & 3) << 6) + d;
    const float4 v = *(const float4*)&YC[bestIdx[row] * F + f];
    // d_out+1 is not 16B-aligned -> scalar stores
    out[1 + g + 0] = v.x;
    out[1 + g + 1] = v.y;
    out[1 + g + 2] = v.z;
    out[1 + g + 3] = v.w;
}

extern "C" void kernel_launch(void* const* d_in, const int* in_sizes, int n_in,
                              void* d_out, int out_size, void* d_ws, size_t ws_size,
                              hipStream_t stream) {
    const float* x = (const float*)d_in[0];
    const float* y = (const float*)d_in[1];
    float* out = (float*)d_out;
    char* ws = (char*)d_ws;
    float* XC      = (float*)(ws);
    float* YC      = (float*)(ws + 33554432u);
    float* partVal = (float*)(ws + 67108864u);
    int*   partIdx = (int*)  (ws + 67371008u);
    int*   bestIdx = (int*)  (ws + 67633152u);
    float* blkSum  = (float*)(ws + 67665920u);

    normKernel<<<16384, 256, 0, stream>>>(x, y, XC, YC);
    simKernel<<<dim3(64, 8), 256, 0, stream>>>(XC, YC, partVal, partIdx);
    reduceKernel<<<32, 256, 0, stream>>>(partVal, partIdx, bestIdx, blkSum);
    gatherKernel<<<8192, 256, 0, stream>>>(YC, bestIdx, blkSum, out);
}

// Round 2
// 777.272 us; speedup vs baseline: 2.2099x; 2.2099x over previous
//
#include <hip/hip_runtime.h>
#include <math.h>

// B=8, W=H=128, D=64, bs=4 -> M=N=8192 rows, F=1024 features.
// Split-bf16 GEMM: x = xhi + xlo (bf16 each). sim = xhi*yhi + xlo*yhi + xhi*ylo
// as one logical K=3072 bf16 MFMA GEMM over physical [hi|lo] K=2048 arrays.
// Worst-case sim error ~1.2e-5 << EPS=2e-4 refine window.

#define NROWS 8192
#define K2 2048
#define KL 3072
#define EPS 2e-4f

typedef __bf16 v8bf __attribute__((ext_vector_type(8)));
typedef __bf16 v4bf __attribute__((ext_vector_type(4)));
typedef float f32x4 __attribute__((ext_vector_type(4)));

#define GLAS(p) ((const __attribute__((address_space(1))) void*)(p))
#define LDSAS(p) ((__attribute__((address_space(3))) void*)(p))

__device__ __forceinline__ double blockReduceAdd(double v) {
    __shared__ double sh[4];
    #pragma unroll
    for (int off = 32; off; off >>= 1) v += __shfl_down(v, off, 64);
    __syncthreads();
    if ((threadIdx.x & 63) == 0) sh[threadIdx.x >> 6] = v;
    __syncthreads();
    return sh[0] + sh[1] + sh[2] + sh[3];
}

// One block per feature-row. Writes [hi(1024)|lo(1024)] bf16 per row.
__global__ __launch_bounds__(256) void normSplitKernel(
    const float* __restrict__ x, const float* __restrict__ y,
    __bf16* __restrict__ Xs, __bf16* __restrict__ Ys, int* __restrict__ flagCnt) {
    if (blockIdx.x == 0 && threadIdx.x == 0) *flagCnt = 0;
    int bi = blockIdx.x;
    const float* src; __bf16* dst; int row;
    if (bi < NROWS) { src = x; dst = Xs; row = bi; }
    else            { src = y; dst = Ys; row = bi - NROWS; }
    int t = threadIdx.x;
    int b = row >> 10, wi = (row >> 5) & 31, hq = row & 31;
    int a = t >> 6, c = (t >> 4) & 3, d = (t & 15) << 2;
    const float4 v = *(const float4*)&src[(((b * 128) + wi * 4 + a) * 128 + hq * 4 + c) * 64 + d];
    double s = (double)v.x + (double)v.y + (double)v.z + (double)v.w;
    double mean = blockReduceAdd(s) * (1.0 / 1024.0);
    double dx = (double)v.x - mean, dy = (double)v.y - mean;
    double dz = (double)v.z - mean, dw = (double)v.w - mean;
    double ss = blockReduceAdd(dx * dx + dy * dy + dz * dz + dw * dw);
    double scale = 1.0 / (sqrt(ss) + 1e-5);
    float f0 = (float)(dx * scale), f1 = (float)(dy * scale);
    float f2 = (float)(dz * scale), f3 = (float)(dw * scale);
    __bf16 h0 = (__bf16)f0, h1 = (__bf16)f1, h2 = (__bf16)f2, h3 = (__bf16)f3;
    __bf16 l0 = (__bf16)(f0 - (float)h0), l1 = (__bf16)(f1 - (float)h1);
    __bf16 l2 = (__bf16)(f2 - (float)h2), l3 = (__bf16)(f3 - (float)h3);
    v4bf hv = {h0, h1, h2, h3}, lv = {l0, l1, l2, l3};
    *(v4bf*)&dst[row * K2 + (t << 2)] = hv;
    *(v4bf*)&dst[row * K2 + 1024 + (t << 2)] = lv;
}

// MFMA GEMM C = Xs * Ys^T (logical K=3072) fused with per-row top-2 argmax.
// 128x128 tile, 256 thr = 4 waves, wave w owns rows [w*32, w*32+32) x all 128 cols.
__global__ __launch_bounds__(256) void simKernel(
    const __bf16* __restrict__ Xs, const __bf16* __restrict__ Ys,
    float* __restrict__ pV1, int* __restrict__ pI1,
    float* __restrict__ pV2, int* __restrict__ pI2) {
    __shared__ __bf16 As[128 * 32];
    __shared__ __bf16 Bs[128 * 32];
    const int t = threadIdx.x;
    const int l = t & 63, w = t >> 6;
    const int quad = l >> 4, lm = l & 15;
    const int r0 = blockIdx.x * 128, c0 = blockIdx.y * 128;

    f32x4 acc[2][8];
    #pragma unroll
    for (int i = 0; i < 2; i++)
        #pragma unroll
        for (int j = 0; j < 8; j++) acc[i][j] = (f32x4){0.f, 0.f, 0.f, 0.f};

    const __bf16* srcA = Xs + (size_t)(r0 + (t >> 2)) * K2 + ((t & 3) << 3);
    const __bf16* srcB = Ys + (size_t)(c0 + (t >> 2)) * K2 + ((t & 3) << 3);
    __bf16* dA0 = As + t * 8;              // rows 0..63
    __bf16* dA1 = As + 2048 + t * 8;       // rows 64..127
    __bf16* dB0 = Bs + t * 8;
    __bf16* dB1 = Bs + 2048 + t * 8;

    for (int kk = 0; kk < KL; kk += 32) {
        const int kA = kk & 2047;                       // [hi|lo|hi]
        const int kB = kk - (kk >= 1024 ? 1024 : 0);    // [hi|hi|lo]
        __syncthreads();
        __builtin_amdgcn_global_load_lds(GLAS(srcA + kA), LDSAS(dA0), 16, 0, 0);
        __builtin_amdgcn_global_load_lds(GLAS(srcA + 64 * K2 + kA), LDSAS(dA1), 16, 0, 0);
        __builtin_amdgcn_global_load_lds(GLAS(srcB + kB), LDSAS(dB0), 16, 0, 0);
        __builtin_amdgcn_global_load_lds(GLAS(srcB + 64 * K2 + kB), LDSAS(dB1), 16, 0, 0);
        __syncthreads();
        v8bf af[2], bfr[8];
        #pragma unroll
        for (int i = 0; i < 2; i++)
            af[i] = *(const v8bf*)&As[(w * 32 + i * 16 + lm) * 32 + quad * 8];
        #pragma unroll
        for (int j = 0; j < 8; j++)
            bfr[j] = *(const v8bf*)&Bs[(j * 16 + lm) * 32 + quad * 8];
        #pragma unroll
        for (int i = 0; i < 2; i++)
            #pragma unroll
            for (int j = 0; j < 8; j++)
                acc[i][j] = __builtin_amdgcn_mfma_f32_16x16x32_bf16(af[i], bfr[j], acc[i][j], 0, 0, 0);
    }

    // Epilogue: per-row top-2 (val,idx). C layout: col=lane&15, row=quad*4+reg.
    const int cb = blockIdx.y;
    #pragma unroll
    for (int i = 0; i < 2; i++) {
        #pragma unroll
        for (int r = 0; r < 4; r++) {
            float v1 = acc[i][0][r]; int i1 = c0 + lm;
            float v2 = -1e30f; int i2 = 0x7fffffff;
            #pragma unroll
            for (int j = 1; j < 8; j++) {
                float v = acc[i][j][r]; int cc = c0 + j * 16 + lm;
                if (v > v1 || (v == v1 && cc < i1)) { v2 = v1; i2 = i1; v1 = v; i1 = cc; }
                else if (v > v2 || (v == v2 && cc < i2)) { v2 = v; i2 = cc; }
            }
            #pragma unroll
            for (int m = 1; m < 16; m <<= 1) {
                float ov1 = __shfl_xor(v1, m, 64); int oi1 = __shfl_xor(i1, m, 64);
                float ov2 = __shfl_xor(v2, m, 64); int oi2 = __shfl_xor(i2, m, 64);
                if (ov1 > v1 || (ov1 == v1 && oi1 < i1)) {
                    if (v1 > ov2 || (v1 == ov2 && i1 < oi2)) { v2 = v1; i2 = i1; }
                    else { v2 = ov2; i2 = oi2; }
                    v1 = ov1; i1 = oi1;
                } else {
                    if (ov1 > v2 || (ov1 == v2 && oi1 < i2)) { v2 = ov1; i2 = oi1; }
                }
            }
            if (lm == 0) {
                int row = r0 + w * 32 + i * 16 + quad * 4 + r;
                pV1[cb * NROWS + row] = v1; pI1[cb * NROWS + row] = i1;
                pV2[cb * NROWS + row] = v2; pI2[cb * NROWS + row] = i2;
            }
        }
    }
}

__global__ __launch_bounds__(256) void reduceKernel(
    const float* __restrict__ pV1, const int* __restrict__ pI1,
    const float* __restrict__ pV2, const int* __restrict__ pI2,
    int* __restrict__ bestIdx, int* __restrict__ flagRows, int* __restrict__ flagAlt,
    int* __restrict__ flagCnt, float* __restrict__ blkSum) {
    int t = threadIdx.x;
    int row = blockIdx.x * 256 + t;
    float B1 = -1e30f, B2 = -1e30f; int I1 = 0x7fffffff, I2 = 0x7fffffff;
    for (int c = 0; c < 64; c++) {
        float v1 = pV1[c * NROWS + row]; int i1 = pI1[c * NROWS + row];
        float v2 = pV2[c * NROWS + row]; int i2 = pI2[c * NROWS + row];
        if (v1 > B1 || (v1 == B1 && i1 < I1)) {
            if (B1 > v2 || (B1 == v2 && I1 < i2)) { B2 = B1; I2 = I1; }
            else { B2 = v2; I2 = i2; }
            B1 = v1; I1 = i1;
        } else {
            if (v1 > B2 || (v1 == B2 && i1 < I2)) { B2 = v1; I2 = i1; }
        }
    }
    bestIdx[row] = I1;
    if (B1 - B2 < EPS) { int s = atomicAdd(flagCnt, 1); flagRows[s] = row; flagAlt[s] = I2; }
    double sum = 1.0 - (double)B1;
    __shared__ double sh[4];
    #pragma unroll
    for (int off = 32; off; off >>= 1) sum += __shfl_down(sum, off, 64);
    if ((t & 63) == 0) sh[t >> 6] = sum;
    __syncthreads();
    if (t == 0) blkSum[blockIdx.x] = (float)(sh[0] + sh[1] + sh[2] + sh[3]);
}

// fp32 re-check of top-2 candidates for near-tie rows.
__global__ __launch_bounds__(256) void refineKernel(
    const __bf16* __restrict__ Xs, const __bf16* __restrict__ Ys,
    int* __restrict__ bestIdx, const int* __restrict__ flagRows,
    const int* __restrict__ flagAlt, const int* __restrict__ flagCnt) {
    int n = *flagCnt;
    int t = threadIdx.x;
    for (int fi = blockIdx.x; fi < n; fi += gridDim.x) {
        int row = flagRows[fi], alt = flagAlt[fi], cur = bestIdx[row];
        int k0 = t << 2;
        double p1 = 0.0, p2 = 0.0;
        #pragma unroll
        for (int q = 0; q < 4; q++) {
            float xv = (float)Xs[(size_t)row * K2 + k0 + q] + (float)Xs[(size_t)row * K2 + 1024 + k0 + q];
            float yc = (float)Ys[(size_t)cur * K2 + k0 + q] + (float)Ys[(size_t)cur * K2 + 1024 + k0 + q];
            float ya = (float)Ys[(size_t)alt * K2 + k0 + q] + (float)Ys[(size_t)alt * K2 + 1024 + k0 + q];
            p1 += (double)xv * yc; p2 += (double)xv * ya;
        }
        double d1 = blockReduceAdd(p1);
        double d2 = blockReduceAdd(p2);
        if (t == 0 && (d2 > d1 || (d2 == d1 && alt < cur))) bestIdx[row] = alt;
    }
}

// new_x gather (hi+lo reconstruct == fp32 codebook) + loss finalize.
__global__ __launch_bounds__(256) void gatherKernel(
    const __bf16* __restrict__ Ys, const int* __restrict__ bestIdx,
    const float* __restrict__ blkSum, float* __restrict__ out) {
    int t = threadIdx.x;
    if (blockIdx.x == 0 && t == 0) {
        double s = 0.0;
        for (int i = 0; i < 32; i++) s += (double)blkSum[i];
        out[0] = (float)(s / 8192.0);
    }
    int g = (blockIdx.x * 256 + t) << 2;
    int b = g >> 20, wq = (g >> 13) & 127, hq = (g >> 6) & 127, d = g & 63;
    int row = (b << 10) + ((wq >> 2) << 5) + (hq >> 2);
    int f = ((wq & 3) << 8) + ((hq & 3) << 6) + d;
    size_t base = (size_t)bestIdx[row] * K2 + f;
    v4bf hv = *(const v4bf*)&Ys[base];
    v4bf lv = *(const v4bf*)&Ys[base + 1024];
    out[1 + g + 0] = (float)hv[0] + (float)lv[0];
    out[1 + g + 1] = (float)hv[1] + (float)lv[1];
    out[1 + g + 2] = (float)hv[2] + (float)lv[2];
    out[1 + g + 3] = (float)hv[3] + (float)lv[3];
}

extern "C" void kernel_launch(void* const* d_in, const int* in_sizes, int n_in,
                              void* d_out, int out_size, void* d_ws, size_t ws_size,
                              hipStream_t stream) {
    const float* x = (const float*)d_in[0];
    const float* y = (const float*)d_in[1];
    float* out = (float*)d_out;
    char* ws = (char*)d_ws;
    __bf16* Xs    = (__bf16*)(ws);
    __bf16* Ys    = (__bf16*)(ws + 33554432u);
    float* pV1    = (float*)(ws + 67108864u);
    float* pV2    = (float*)(ws + 69206016u);
    int*   pI1    = (int*)  (ws + 71303168u);
    int*   pI2    = (int*)  (ws + 73400320u);
    int* bestIdx  = (int*)  (ws + 75497472u);
    int* flagRows = (int*)  (ws + 75530240u);
    int* flagAlt  = (int*)  (ws + 75563008u);
    int* flagCnt  = (int*)  (ws + 75595776u);
    float* blkSum = (float*)(ws + 75595904u);

    normSplitKernel<<<16384, 256, 0, stream>>>(x, y, Xs, Ys, flagCnt);
    simKernel<<<dim3(64, 64), 256, 0, stream>>>(Xs, Ys, pV1, pI1, pV2, pI2);
    reduceKernel<<<32, 256, 0, stream>>>(pV1, pI1, pV2, pI2, bestIdx, flagRows, flagAlt, flagCnt, blkSum);
    refineKernel<<<64, 256, 0, stream>>>(Xs, Ys, bestIdx, flagRows, flagAlt, flagCnt);
    gatherKernel<<<8192, 256, 0, stream>>>(Ys, bestIdx, blkSum, out);
}

// Round 3
// 646.426 us; speedup vs baseline: 2.6572x; 1.2024x over previous
//
#include <hip/hip_runtime.h>
#include <math.h>

// B=8, W=H=128, D=64, bs=4 -> M=N=8192 rows, F=1024 features.
// fp16 2-term split GEMM: x = xhi + xlo (fp16 each, |x|<=1 after normalize).
// sim = xhi*yhi + xlo*yhi  (dropped xhi*ylo ~ 2^-11 scale, err std ~1.5e-5).
// Logical K=2048 over Xs=[hi|lo] (K=2048) and Yh (K=1024, read twice).
// Top-2 tracking + fp32 refine for rows with gap < EPS keeps argmax exact.

#define NROWS 8192
#define KX 2048   // X physical K: [hi|lo]
#define KY 1024   // Y hi-only K
#define NCH 128   // col partial chunks (64 blocks.y * 2 waves)
#define EPS 1e-3f

typedef _Float16 v8h __attribute__((ext_vector_type(8)));
typedef float f32x4 __attribute__((ext_vector_type(4)));

#define GLAS(p) ((const __attribute__((address_space(1))) void*)(p))
#define LDSAS(p) ((__attribute__((address_space(3))) void*)(p))

// One 64-lane wave per feature-row; 16 floats/lane; shuffle-only reductions.
__global__ __launch_bounds__(256) void normSplitKernel(
    const float* __restrict__ x, const float* __restrict__ y,
    _Float16* __restrict__ Xs, _Float16* __restrict__ Yh, _Float16* __restrict__ Yl,
    int* __restrict__ flagCnt) {
    if (blockIdx.x == 0 && threadIdx.x == 0) *flagCnt = 0;
    int gr = blockIdx.x * 4 + (threadIdx.x >> 6);   // 0..16383
    int ln = threadIdx.x & 63;
    bool isX = gr < NROWS;
    int row = isX ? gr : gr - NROWS;
    const float* src = isX ? x : y;
    int b = row >> 10, wq = (row >> 5) & 31, hq = row & 31;
    int a = ln >> 4, c = (ln & 15) >> 2, d0 = (ln & 3) << 4;
    const float* p = &src[(((size_t)(b * 128) + wq * 4 + a) * 128 + hq * 4 + c) * 64 + d0];
    float vv[16];
    *(float4*)(vv + 0)  = *(const float4*)(p + 0);
    *(float4*)(vv + 4)  = *(const float4*)(p + 4);
    *(float4*)(vv + 8)  = *(const float4*)(p + 8);
    *(float4*)(vv + 12) = *(const float4*)(p + 12);
    double s = 0.0;
    #pragma unroll
    for (int q = 0; q < 16; q++) s += (double)vv[q];
    #pragma unroll
    for (int m = 1; m < 64; m <<= 1) s += __shfl_xor(s, m, 64);
    double mean = s * (1.0 / 1024.0);
    double ss = 0.0;
    #pragma unroll
    for (int q = 0; q < 16; q++) {
        double d = (double)vv[q] - mean;
        ss += d * d;
    }
    #pragma unroll
    for (int m = 1; m < 64; m <<= 1) ss += __shfl_xor(ss, m, 64);
    double scale = 1.0 / (sqrt(ss) + 1e-5);
    _Float16 hi[16], lo[16];
    #pragma unroll
    for (int q = 0; q < 16; q++) {
        float f = (float)(((double)vv[q] - mean) * scale);
        _Float16 h = (_Float16)f;
        hi[q] = h;
        lo[q] = (_Float16)(f - (float)h);
    }
    int f0 = ln << 4;
    if (isX) {
        *(v8h*)&Xs[(size_t)row * KX + f0]            = *(v8h*)(hi);
        *(v8h*)&Xs[(size_t)row * KX + f0 + 8]        = *(v8h*)(hi + 8);
        *(v8h*)&Xs[(size_t)row * KX + 1024 + f0]     = *(v8h*)(lo);
        *(v8h*)&Xs[(size_t)row * KX + 1024 + f0 + 8] = *(v8h*)(lo + 8);
    } else {
        *(v8h*)&Yh[(size_t)row * KY + f0]     = *(v8h*)(hi);
        *(v8h*)&Yh[(size_t)row * KY + f0 + 8] = *(v8h*)(hi + 8);
        *(v8h*)&Yl[(size_t)row * KY + f0]     = *(v8h*)(lo);
        *(v8h*)&Yl[(size_t)row * KY + f0 + 8] = *(v8h*)(lo + 8);
    }
}

// MFMA GEMM C = Xs * [Yh|Yh]^T (logical K=2048) fused per-row top-2 argmax.
// 128x128 tile, 4 waves in 2x2, each wave 64x64 (4x4 frags of 16x16x32).
// Single barrier per k-step; double-buffered LDS with post-barrier prefetch.
__global__ __launch_bounds__(256) void simKernel(
    const _Float16* __restrict__ Xs, const _Float16* __restrict__ Yh,
    float* __restrict__ pV1, int* __restrict__ pI1,
    float* __restrict__ pV2, int* __restrict__ pI2) {
    __shared__ _Float16 As[2][128 * 32];
    __shared__ _Float16 Bs[2][128 * 32];
    const int t = threadIdx.x;
    const int l = t & 63, w = t >> 6;
    const int wr = w >> 1, wc = w & 1;
    const int quad = l >> 4, lm = l & 15;
    const int r0 = blockIdx.x * 128, c0 = blockIdx.y * 128;

    f32x4 acc[4][4];
    #pragma unroll
    for (int i = 0; i < 4; i++)
        #pragma unroll
        for (int j = 0; j < 4; j++) acc[i][j] = (f32x4){0.f, 0.f, 0.f, 0.f};

    const _Float16* srcA0 = Xs + (size_t)(r0 + (t >> 2)) * KX + ((t & 3) << 3);
    const _Float16* srcA1 = srcA0 + (size_t)64 * KX;
    const _Float16* srcB0 = Yh + (size_t)(c0 + (t >> 2)) * KY + ((t & 3) << 3);
    const _Float16* srcB1 = srcB0 + (size_t)64 * KY;
    const int st8 = t * 8;

    // prologue: k-step 0 into buffer 0
    __builtin_amdgcn_global_load_lds(GLAS(srcA0), LDSAS(&As[0][st8]), 16, 0, 0);
    __builtin_amdgcn_global_load_lds(GLAS(srcA1), LDSAS(&As[0][2048 + st8]), 16, 0, 0);
    __builtin_amdgcn_global_load_lds(GLAS(srcB0), LDSAS(&Bs[0][st8]), 16, 0, 0);
    __builtin_amdgcn_global_load_lds(GLAS(srcB1), LDSAS(&Bs[0][2048 + st8]), 16, 0, 0);

    const int offA0 = (wr * 64 + lm) * 32 + quad * 8;
    const int offB0 = (wc * 64 + lm) * 32 + quad * 8;

    for (int kk = 0; kk < KX; kk += 32) {
        const int cb = (kk >> 5) & 1;
        __syncthreads();   // compiler emits vmcnt(0) drain: buf[cb] DMA complete
        if (kk + 32 < KX) {
            const int nb = cb ^ 1;
            const int kn = kk + 32, knB = kn & (KY - 1);
            __builtin_amdgcn_global_load_lds(GLAS(srcA0 + kn), LDSAS(&As[nb][st8]), 16, 0, 0);
            __builtin_amdgcn_global_load_lds(GLAS(srcA1 + kn), LDSAS(&As[nb][2048 + st8]), 16, 0, 0);
            __builtin_amdgcn_global_load_lds(GLAS(srcB0 + knB), LDSAS(&Bs[nb][st8]), 16, 0, 0);
            __builtin_amdgcn_global_load_lds(GLAS(srcB1 + knB), LDSAS(&Bs[nb][2048 + st8]), 16, 0, 0);
        }
        v8h af[4], bf[4];
        #pragma unroll
        for (int i = 0; i < 4; i++)
            af[i] = *(const v8h*)&As[cb][offA0 + i * 512];
        #pragma unroll
        for (int j = 0; j < 4; j++)
            bf[j] = *(const v8h*)&Bs[cb][offB0 + j * 512];
        #pragma unroll
        for (int i = 0; i < 4; i++)
            #pragma unroll
            for (int j = 0; j < 4; j++)
                acc[i][j] = __builtin_amdgcn_mfma_f32_16x16x32_f16(af[i], bf[j], acc[i][j], 0, 0, 0);
    }

    // Epilogue: per-row top-2. C layout: col=lane&15, row=quad*4+reg.
    const int cch = blockIdx.y * 2 + wc;
    const int cbase = c0 + wc * 64 + lm;
    #pragma unroll
    for (int i = 0; i < 4; i++) {
        #pragma unroll
        for (int r = 0; r < 4; r++) {
            float v1 = acc[i][0][r]; int i1 = cbase;
            float v2 = -1e30f; int i2 = 0x7fffffff;
            #pragma unroll
            for (int j = 1; j < 4; j++) {
                float v = acc[i][j][r]; int cc = cbase + j * 16;
                if (v > v1 || (v == v1 && cc < i1)) { v2 = v1; i2 = i1; v1 = v; i1 = cc; }
                else if (v > v2 || (v == v2 && cc < i2)) { v2 = v; i2 = cc; }
            }
            #pragma unroll
            for (int m = 1; m < 16; m <<= 1) {
                float ov1 = __shfl_xor(v1, m, 64); int oi1 = __shfl_xor(i1, m, 64);
                float ov2 = __shfl_xor(v2, m, 64); int oi2 = __shfl_xor(i2, m, 64);
                if (ov1 > v1 || (ov1 == v1 && oi1 < i1)) {
                    if (v1 > ov2 || (v1 == ov2 && i1 < oi2)) { v2 = v1; i2 = i1; }
                    else { v2 = ov2; i2 = oi2; }
                    v1 = ov1; i1 = oi1;
                } else {
                    if (ov1 > v2 || (ov1 == v2 && oi1 < i2)) { v2 = ov1; i2 = oi1; }
                }
            }
            if (lm == 0) {
                int row = r0 + wr * 64 + i * 16 + quad * 4 + r;
                pV1[(size_t)cch * NROWS + row] = v1; pI1[(size_t)cch * NROWS + row] = i1;
                pV2[(size_t)cch * NROWS + row] = v2; pI2[(size_t)cch * NROWS + row] = i2;
            }
        }
    }
}

__global__ __launch_bounds__(256) void reduceKernel(
    const float* __restrict__ pV1, const int* __restrict__ pI1,
    const float* __restrict__ pV2, const int* __restrict__ pI2,
    int* __restrict__ bestIdx, int* __restrict__ flagRows, int* __restrict__ flagAlt,
    int* __restrict__ flagCnt, float* __restrict__ blkSum) {
    int t = threadIdx.x;
    int row = blockIdx.x * 256 + t;
    float B1 = -1e30f, B2 = -1e30f; int I1 = 0x7fffffff, I2 = 0x7fffffff;
    for (int c = 0; c < NCH; c++) {
        float v1 = pV1[(size_t)c * NROWS + row]; int i1 = pI1[(size_t)c * NROWS + row];
        float v2 = pV2[(size_t)c * NROWS + row]; int i2 = pI2[(size_t)c * NROWS + row];
        if (v1 > B1 || (v1 == B1 && i1 < I1)) {
            if (B1 > v2 || (B1 == v2 && I1 < i2)) { B2 = B1; I2 = I1; }
            else { B2 = v2; I2 = i2; }
            B1 = v1; I1 = i1;
        } else {
            if (v1 > B2 || (v1 == B2 && i1 < I2)) { B2 = v1; I2 = i1; }
        }
    }
    bestIdx[row] = I1;
    if (B1 - B2 < EPS) { int s = atomicAdd(flagCnt, 1); flagRows[s] = row; flagAlt[s] = I2; }
    double sum = 1.0 - (double)B1;
    __shared__ double sh[4];
    #pragma unroll
    for (int off = 32; off; off >>= 1) sum += __shfl_down(sum, off, 64);
    if ((t & 63) == 0) sh[t >> 6] = sum;
    __syncthreads();
    if (t == 0) blkSum[blockIdx.x] = (float)(sh[0] + sh[1] + sh[2] + sh[3]);
}

// fp32/fp64 re-check of top-2 candidates for near-tie rows; one wave per row.
__global__ __launch_bounds__(256) void refineKernel(
    const _Float16* __restrict__ Xs, const _Float16* __restrict__ Yh,
    const _Float16* __restrict__ Yl, int* __restrict__ bestIdx,
    const int* __restrict__ flagRows, const int* __restrict__ flagAlt,
    const int* __restrict__ flagCnt) {
    int n = *flagCnt;
    int wave = (blockIdx.x << 2) + (threadIdx.x >> 6);
    int ln = threadIdx.x & 63;
    for (int fi = wave; fi < n; fi += gridDim.x * 4) {
        int row = flagRows[fi], alt = flagAlt[fi], cur = bestIdx[row];
        double p1 = 0.0, p2 = 0.0;
        #pragma unroll
        for (int q = 0; q < 16; q++) {
            int k = (ln << 4) + q;
            float xv = (float)Xs[(size_t)row * KX + k] + (float)Xs[(size_t)row * KX + 1024 + k];
            float yc = (float)Yh[(size_t)cur * KY + k] + (float)Yl[(size_t)cur * KY + k];
            float ya = (float)Yh[(size_t)alt * KY + k] + (float)Yl[(size_t)alt * KY + k];
            p1 += (double)xv * yc; p2 += (double)xv * ya;
        }
        #pragma unroll
        for (int m = 1; m < 64; m <<= 1) {
            p1 += __shfl_xor(p1, m, 64);
            p2 += __shfl_xor(p2, m, 64);
        }
        if (ln == 0 && (p2 > p1 || (p2 == p1 && alt < cur))) bestIdx[row] = alt;
    }
}

// new_x gather (hi+lo reconstruct ~ fp32 codebook) + loss finalize.
__global__ __launch_bounds__(256) void gatherKernel(
    const _Float16* __restrict__ Yh, const _Float16* __restrict__ Yl,
    const int* __restrict__ bestIdx, const float* __restrict__ blkSum,
    float* __restrict__ out) {
    int t = threadIdx.x;
    if (blockIdx.x == 0 && t == 0) {
        double s = 0.0;
        for (int i = 0; i < 32; i++) s += (double)blkSum[i];
        out[0] = (float)(s / 8192.0);
    }
    int g = (blockIdx.x * 256 + t) << 2;
    int b = g >> 20, wq = (g >> 13) & 127, hq = (g >> 6) & 127, d = g & 63;
    int row = (b << 10) + ((wq >> 2) << 5) + (hq >> 2);
    int f = ((wq & 3) << 8) + ((hq & 3) << 6) + d;
    size_t base = (size_t)bestIdx[row] * KY + f;
    v8h hv4; float4 o;
    const _Float16* ph = &Yh[base];
    const _Float16* pl = &Yl[base];
    o.x = (float)ph[0] + (float)pl[0];
    o.y = (float)ph[1] + (float)pl[1];
    o.z = (float)ph[2] + (float)pl[2];
    o.w = (float)ph[3] + (float)pl[3];
    out[1 + g + 0] = o.x;
    out[1 + g + 1] = o.y;
    out[1 + g + 2] = o.z;
    out[1 + g + 3] = o.w;
    (void)hv4;
}

extern "C" void kernel_launch(void* const* d_in, const int* in_sizes, int n_in,
                              void* d_out, int out_size, void* d_ws, size_t ws_size,
                              hipStream_t stream) {
    const float* x = (const float*)d_in[0];
    const float* y = (const float*)d_in[1];
    float* out = (float*)d_out;
    char* ws = (char*)d_ws;
    _Float16* Xs  = (_Float16*)(ws);
    _Float16* Yh  = (_Float16*)(ws + 33554432u);
    _Float16* Yl  = (_Float16*)(ws + 50331648u);
    float* pV1    = (float*)(ws + 67108864u);
    float* pV2    = (float*)(ws + 71303168u);
    int*   pI1    = (int*)  (ws + 75497472u);
    int*   pI2    = (int*)  (ws + 79691776u);
    int* bestIdx  = (int*)  (ws + 83886080u);
    int* flagRows = (int*)  (ws + 83918848u);
    int* flagAlt  = (int*)  (ws + 83951616u);
    int* flagCnt  = (int*)  (ws + 83984384u);
    float* blkSum = (float*)(ws + 83984512u);

    normSplitKernel<<<4096, 256, 0, stream>>>(x, y, Xs, Yh, Yl, flagCnt);
    simKernel<<<dim3(64, 64), 256, 0, stream>>>(Xs, Yh, pV1, pI1, pV2, pI2);
    reduceKernel<<<32, 256, 0, stream>>>(pV1, pI1, pV2, pI2, bestIdx, flagRows, flagAlt, flagCnt, blkSum);
    refineKernel<<<64, 256, 0, stream>>>(Xs, Yh, Yl, bestIdx, flagRows, flagAlt, flagCnt);
    gatherKernel<<<8192, 256, 0, stream>>>(Yh, Yl, bestIdx, blkSum, out);
}

// Round 4
// 583.081 us; speedup vs baseline: 2.9459x; 1.1086x over previous
//
#include <hip/hip_runtime.h>
#include <math.h>

// B=8, W=H=128, D=64, bs=4 -> M=N=8192 rows, F=1024 features.
// fp16 2-term split GEMM: x = xhi + xlo (fp16 each, |x|<=1 after normalize).
// sim = xhi*yhi + xlo*yhi  (dropped xhi*ylo ~ 2^-11 scale, err std ~1.5e-5).
// Logical K=2048 over Xs=[hi|lo] (K=2048) and Yh (K=1024, read twice).
// Top-2 tracking + fp32 refine for rows with gap < EPS keeps argmax exact.
// R4: register-staged prefetch (plain global loads -> VGPR -> ds_write) so
// s_barrier needs lgkmcnt only; the vmcnt wait lands after the MFMA phase.

#define NROWS 8192
#define KX 2048   // X physical K: [hi|lo]
#define KY 1024   // Y hi-only K
#define NCH 128   // col partial chunks (64 col tiles * 2 waves)
#define EPS 1e-3f

typedef _Float16 v8h __attribute__((ext_vector_type(8)));
typedef float f32x4 __attribute__((ext_vector_type(4)));

// One 64-lane wave per feature-row; 16 floats/lane; shuffle-only reductions.
__global__ __launch_bounds__(256) void normSplitKernel(
    const float* __restrict__ x, const float* __restrict__ y,
    _Float16* __restrict__ Xs, _Float16* __restrict__ Yh, _Float16* __restrict__ Yl,
    int* __restrict__ flagCnt) {
    if (blockIdx.x == 0 && threadIdx.x == 0) *flagCnt = 0;
    int gr = blockIdx.x * 4 + (threadIdx.x >> 6);   // 0..16383
    int ln = threadIdx.x & 63;
    bool isX = gr < NROWS;
    int row = isX ? gr : gr - NROWS;
    const float* src = isX ? x : y;
    int b = row >> 10, wq = (row >> 5) & 31, hq = row & 31;
    int a = ln >> 4, c = (ln & 15) >> 2, d0 = (ln & 3) << 4;
    const float* p = &src[(((size_t)(b * 128) + wq * 4 + a) * 128 + hq * 4 + c) * 64 + d0];
    float vv[16];
    *(float4*)(vv + 0)  = *(const float4*)(p + 0);
    *(float4*)(vv + 4)  = *(const float4*)(p + 4);
    *(float4*)(vv + 8)  = *(const float4*)(p + 8);
    *(float4*)(vv + 12) = *(const float4*)(p + 12);
    double s = 0.0;
    #pragma unroll
    for (int q = 0; q < 16; q++) s += (double)vv[q];
    #pragma unroll
    for (int m = 1; m < 64; m <<= 1) s += __shfl_xor(s, m, 64);
    double mean = s * (1.0 / 1024.0);
    double ss = 0.0;
    #pragma unroll
    for (int q = 0; q < 16; q++) {
        double d = (double)vv[q] - mean;
        ss += d * d;
    }
    #pragma unroll
    for (int m = 1; m < 64; m <<= 1) ss += __shfl_xor(ss, m, 64);
    double scale = 1.0 / (sqrt(ss) + 1e-5);
    _Float16 hi[16], lo[16];
    #pragma unroll
    for (int q = 0; q < 16; q++) {
        float f = (float)(((double)vv[q] - mean) * scale);
        _Float16 h = (_Float16)f;
        hi[q] = h;
        lo[q] = (_Float16)(f - (float)h);
    }
    int f0 = ln << 4;
    if (isX) {
        *(v8h*)&Xs[(size_t)row * KX + f0]            = *(v8h*)(hi);
        *(v8h*)&Xs[(size_t)row * KX + f0 + 8]        = *(v8h*)(hi + 8);
        *(v8h*)&Xs[(size_t)row * KX + 1024 + f0]     = *(v8h*)(lo);
        *(v8h*)&Xs[(size_t)row * KX + 1024 + f0 + 8] = *(v8h*)(lo + 8);
    } else {
        *(v8h*)&Yh[(size_t)row * KY + f0]     = *(v8h*)(hi);
        *(v8h*)&Yh[(size_t)row * KY + f0 + 8] = *(v8h*)(hi + 8);
        *(v8h*)&Yl[(size_t)row * KY + f0]     = *(v8h*)(lo);
        *(v8h*)&Yl[(size_t)row * KY + f0 + 8] = *(v8h*)(lo + 8);
    }
}

// MFMA GEMM C = Xs * [Yh|Yh]^T (logical K=2048) fused per-row top-2 argmax.
// 128x128 tile, 4 waves in 2x2, each wave 64x64 (4x4 frags of 16x16x32).
// Register-staged double-buffer: global->VGPR prefetch overlaps MFMA phase;
// ds_write (with its vmcnt wait) happens after compute; barrier is lgkm-only.
__global__ __launch_bounds__(256) void simKernel(
    const _Float16* __restrict__ Xs, const _Float16* __restrict__ Yh,
    float* __restrict__ pV1, int* __restrict__ pI1,
    float* __restrict__ pV2, int* __restrict__ pI2) {
    __shared__ _Float16 As[2][128 * 32];
    __shared__ _Float16 Bs[2][128 * 32];
    const int t = threadIdx.x;
    const int l = t & 63, w = t >> 6;
    const int wr = w >> 1, wc = w & 1;
    const int quad = l >> 4, lm = l & 15;
    // grid transpose: consecutive flat ids share the A row-tile
    const int flat = blockIdx.y * 64 + blockIdx.x;
    const int bx = flat >> 6, by = flat & 63;
    const int r0 = bx * 128, c0 = by * 128;

    f32x4 acc[4][4];
    #pragma unroll
    for (int i = 0; i < 4; i++)
        #pragma unroll
        for (int j = 0; j < 4; j++) acc[i][j] = (f32x4){0.f, 0.f, 0.f, 0.f};

    const _Float16* srcA0 = Xs + (size_t)(r0 + (t >> 2)) * KX + ((t & 3) << 3);
    const _Float16* srcA1 = srcA0 + (size_t)64 * KX;
    const _Float16* srcB0 = Yh + (size_t)(c0 + (t >> 2)) * KY + ((t & 3) << 3);
    const _Float16* srcB1 = srcB0 + (size_t)64 * KY;
    const int st8 = t * 8;

    // prologue: stage k=0 through regs into buffer 0
    {
        uint4 a0 = *(const uint4*)srcA0;
        uint4 a1 = *(const uint4*)srcA1;
        uint4 b0 = *(const uint4*)srcB0;
        uint4 b1 = *(const uint4*)srcB1;
        *(uint4*)&As[0][st8] = a0;
        *(uint4*)&As[0][2048 + st8] = a1;
        *(uint4*)&Bs[0][st8] = b0;
        *(uint4*)&Bs[0][2048 + st8] = b1;
    }
    __syncthreads();

    const int offA0 = (wr * 64 + lm) * 32 + quad * 8;
    const int offB0 = (wc * 64 + lm) * 32 + quad * 8;

    #pragma unroll 1
    for (int kk = 0; kk < KX - 32; kk += 32) {
        const int cur = (kk >> 5) & 1, nxt = cur ^ 1;
        const int kn = kk + 32, knB = kn & (KY - 1);
        // prefetch next k-step into registers (vmcnt pending through compute)
        uint4 na0 = *(const uint4*)(srcA0 + kn);
        uint4 na1 = *(const uint4*)(srcA1 + kn);
        uint4 nb0 = *(const uint4*)(srcB0 + knB);
        uint4 nb1 = *(const uint4*)(srcB1 + knB);
        // compute on current buffer
        v8h af[4], bf[4];
        #pragma unroll
        for (int i = 0; i < 4; i++)
            af[i] = *(const v8h*)&As[cur][offA0 + i * 512];
        #pragma unroll
        for (int j = 0; j < 4; j++)
            bf[j] = *(const v8h*)&Bs[cur][offB0 + j * 512];
        #pragma unroll
        for (int i = 0; i < 4; i++)
            #pragma unroll
            for (int j = 0; j < 4; j++)
                acc[i][j] = __builtin_amdgcn_mfma_f32_16x16x32_f16(af[i], bf[j], acc[i][j], 0, 0, 0);
        // drain regs -> next buffer (vmcnt wait here, after the MFMA phase)
        *(uint4*)&As[nxt][st8] = na0;
        *(uint4*)&As[nxt][2048 + st8] = na1;
        *(uint4*)&Bs[nxt][st8] = nb0;
        *(uint4*)&Bs[nxt][2048 + st8] = nb1;
        __syncthreads();   // lgkmcnt-only drain (no LDS-DMA outstanding)
    }
    {   // final k-step: compute on buffer 1
        v8h af[4], bf[4];
        #pragma unroll
        for (int i = 0; i < 4; i++)
            af[i] = *(const v8h*)&As[1][offA0 + i * 512];
        #pragma unroll
        for (int j = 0; j < 4; j++)
            bf[j] = *(const v8h*)&Bs[1][offB0 + j * 512];
        #pragma unroll
        for (int i = 0; i < 4; i++)
            #pragma unroll
            for (int j = 0; j < 4; j++)
                acc[i][j] = __builtin_amdgcn_mfma_f32_16x16x32_f16(af[i], bf[j], acc[i][j], 0, 0, 0);
    }

    // Epilogue: per-row top-2. C layout: col=lane&15, row=quad*4+reg.
    const int cch = by * 2 + wc;
    const int cbase = c0 + wc * 64 + lm;
    #pragma unroll
    for (int i = 0; i < 4; i++) {
        #pragma unroll
        for (int r = 0; r < 4; r++) {
            float v1 = acc[i][0][r]; int i1 = cbase;
            float v2 = -1e30f; int i2 = 0x7fffffff;
            #pragma unroll
            for (int j = 1; j < 4; j++) {
                float v = acc[i][j][r]; int cc = cbase + j * 16;
                if (v > v1 || (v == v1 && cc < i1)) { v2 = v1; i2 = i1; v1 = v; i1 = cc; }
                else if (v > v2 || (v == v2 && cc < i2)) { v2 = v; i2 = cc; }
            }
            #pragma unroll
            for (int m = 1; m < 16; m <<= 1) {
                float ov1 = __shfl_xor(v1, m, 64); int oi1 = __shfl_xor(i1, m, 64);
                float ov2 = __shfl_xor(v2, m, 64); int oi2 = __shfl_xor(i2, m, 64);
                if (ov1 > v1 || (ov1 == v1 && oi1 < i1)) {
                    if (v1 > ov2 || (v1 == ov2 && i1 < oi2)) { v2 = v1; i2 = i1; }
                    else { v2 = ov2; i2 = oi2; }
                    v1 = ov1; i1 = oi1;
                } else {
                    if (ov1 > v2 || (ov1 == v2 && oi1 < i2)) { v2 = ov1; i2 = oi1; }
                }
            }
            if (lm == 0) {
                int row = r0 + wr * 64 + i * 16 + quad * 4 + r;
                pV1[(size_t)cch * NROWS + row] = v1; pI1[(size_t)cch * NROWS + row] = i1;
                pV2[(size_t)cch * NROWS + row] = v2; pI2[(size_t)cch * NROWS + row] = i2;
            }
        }
    }
}

__global__ __launch_bounds__(256) void reduceKernel(
    const float* __restrict__ pV1, const int* __restrict__ pI1,
    const float* __restrict__ pV2, const int* __restrict__ pI2,
    int* __restrict__ bestIdx, int* __restrict__ flagRows, int* __restrict__ flagAlt,
    int* __restrict__ flagCnt, float* __restrict__ blkSum) {
    int t = threadIdx.x;
    int row = blockIdx.x * 256 + t;
    float B1 = -1e30f, B2 = -1e30f; int I1 = 0x7fffffff, I2 = 0x7fffffff;
    for (int c = 0; c < NCH; c++) {
        float v1 = pV1[(size_t)c * NROWS + row]; int i1 = pI1[(size_t)c * NROWS + row];
        float v2 = pV2[(size_t)c * NROWS + row]; int i2 = pI2[(size_t)c * NROWS + row];
        if (v1 > B1 || (v1 == B1 && i1 < I1)) {
            if (B1 > v2 || (B1 == v2 && I1 < i2)) { B2 = B1; I2 = I1; }
            else { B2 = v2; I2 = i2; }
            B1 = v1; I1 = i1;
        } else {
            if (v1 > B2 || (v1 == B2 && i1 < I2)) { B2 = v1; I2 = i1; }
        }
    }
    bestIdx[row] = I1;
    if (B1 - B2 < EPS) { int s = atomicAdd(flagCnt, 1); flagRows[s] = row; flagAlt[s] = I2; }
    double sum = 1.0 - (double)B1;
    __shared__ double sh[4];
    #pragma unroll
    for (int off = 32; off; off >>= 1) sum += __shfl_down(sum, off, 64);
    if ((t & 63) == 0) sh[t >> 6] = sum;
    __syncthreads();
    if (t == 0) blkSum[blockIdx.x] = (float)(sh[0] + sh[1] + sh[2] + sh[3]);
}

// fp32/fp64 re-check of top-2 candidates for near-tie rows; one wave per row.
__global__ __launch_bounds__(256) void refineKernel(
    const _Float16* __restrict__ Xs, const _Float16* __restrict__ Yh,
    const _Float16* __restrict__ Yl, int* __restrict__ bestIdx,
    const int* __restrict__ flagRows, const int* __restrict__ flagAlt,
    const int* __restrict__ flagCnt) {
    int n = *flagCnt;
    int wave = (blockIdx.x << 2) + (threadIdx.x >> 6);
    int ln = threadIdx.x & 63;
    for (int fi = wave; fi < n; fi += gridDim.x * 4) {
        int row = flagRows[fi], alt = flagAlt[fi], cur = bestIdx[row];
        double p1 = 0.0, p2 = 0.0;
        #pragma unroll
        for (int q = 0; q < 16; q++) {
            int k = (ln << 4) + q;
            float xv = (float)Xs[(size_t)row * KX + k] + (float)Xs[(size_t)row * KX + 1024 + k];
            float yc = (float)Yh[(size_t)cur * KY + k] + (float)Yl[(size_t)cur * KY + k];
            float ya = (float)Yh[(size_t)alt * KY + k] + (float)Yl[(size_t)alt * KY + k];
            p1 += (double)xv * yc; p2 += (double)xv * ya;
        }
        #pragma unroll
        for (int m = 1; m < 64; m <<= 1) {
            p1 += __shfl_xor(p1, m, 64);
            p2 += __shfl_xor(p2, m, 64);
        }
        if (ln == 0 && (p2 > p1 || (p2 == p1 && alt < cur))) bestIdx[row] = alt;
    }
}

// new_x gather (hi+lo reconstruct ~ fp32 codebook) + loss finalize.
__global__ __launch_bounds__(256) void gatherKernel(
    const _Float16* __restrict__ Yh, const _Float16* __restrict__ Yl,
    const int* __restrict__ bestIdx, const float* __restrict__ blkSum,
    float* __restrict__ out) {
    int t = threadIdx.x;
    if (blockIdx.x == 0 && t == 0) {
        double s = 0.0;
        for (int i = 0; i < 32; i++) s += (double)blkSum[i];
        out[0] = (float)(s / 8192.0);
    }
    int g = (blockIdx.x * 256 + t) << 2;
    int b = g >> 20, wq = (g >> 13) & 127, hq = (g >> 6) & 127, d = g & 63;
    int row = (b << 10) + ((wq >> 2) << 5) + (hq >> 2);
    int f = ((wq & 3) << 8) + ((hq & 3) << 6) + d;
    size_t base = (size_t)bestIdx[row] * KY + f;
    const _Float16* ph = &Yh[base];
    const _Float16* pl = &Yl[base];
    out[1 + g + 0] = (float)ph[0] + (float)pl[0];
    out[1 + g + 1] = (float)ph[1] + (float)pl[1];
    out[1 + g + 2] = (float)ph[2] + (float)pl[2];
    out[1 + g + 3] = (float)ph[3] + (float)pl[3];
}

extern "C" void kernel_launch(void* const* d_in, const int* in_sizes, int n_in,
                              void* d_out, int out_size, void* d_ws, size_t ws_size,
                              hipStream_t stream) {
    const float* x = (const float*)d_in[0];
    const float* y = (const float*)d_in[1];
    float* out = (float*)d_out;
    char* ws = (char*)d_ws;
    _Float16* Xs  = (_Float16*)(ws);
    _Float16* Yh  = (_Float16*)(ws + 33554432u);
    _Float16* Yl  = (_Float16*)(ws + 50331648u);
    float* pV1    = (float*)(ws + 67108864u);
    float* pV2    = (float*)(ws + 71303168u);
    int*   pI1    = (int*)  (ws + 75497472u);
    int*   pI2    = (int*)  (ws + 79691776u);
    int* bestIdx  = (int*)  (ws + 83886080u);
    int* flagRows = (int*)  (ws + 83918848u);
    int* flagAlt  = (int*)  (ws + 83951616u);
    int* flagCnt  = (int*)  (ws + 83984384u);
    float* blkSum = (float*)(ws + 83984512u);

    normSplitKernel<<<4096, 256, 0, stream>>>(x, y, Xs, Yh, Yl, flagCnt);
    simKernel<<<dim3(64, 64), 256, 0, stream>>>(Xs, Yh, pV1, pI1, pV2, pI2);
    reduceKernel<<<32, 256, 0, stream>>>(pV1, pI1, pV2, pI2, bestIdx, flagRows, flagAlt, flagCnt, blkSum);
    refineKernel<<<64, 256, 0, stream>>>(Xs, Yh, Yl, bestIdx, flagRows, flagAlt, flagCnt);
    gatherKernel<<<8192, 256, 0, stream>>>(Yh, Yl, bestIdx, blkSum, out);
}